// Round 5
// baseline (249.198 us; speedup 1.0000x reference)
//
#include <hip/hip_runtime.h>

// GINConv fused: out[r] = (sum_{j<16} X[col[16r+j]]) @ W
// N=100000, DEG=16, D=128. R5: dur tracks FETCH/~3TB/s (R1-R4), and FETCH=175MB
// equals per-XCD compulsory unique-row traffic (86.5k rows x 256B x 8 XCDs).
// Fix: K-slice X into 8 slice-major chunks of 3.2MB; block b -> slice b&7 ->
// XCD b%8 (round-robin heuristic), so each slice is L2-resident on ONE XCD.
// Slices are disjoint in K => X' columns written disjointly, then dense MFMA.

#define NNODES 100000
#define DEG 16
#define D 128

#define NSLICE 8
#define SLICE_C 16                         // cols per slice
#define SLICE_ELEMS (NNODES * SLICE_C)     // 1.6M ushorts per slice

#define XS_BYTES (100000L * 128 * 2)       // 25,600,000  slice-major bf16 X
#define XP_BYTES (100000L * 128 * 2)       // 25,600,000  row-major bf16 X'
#define WT_BYTES (128L * 128 * 2)          // 32,768
#define WS_NEW (XS_BYTES + XP_BYTES + WT_BYTES)
#define WS_R4  (XS_BYTES + WT_BYTES)       // fallback: row-major bf16 X + Wt

typedef __attribute__((ext_vector_type(8))) short bf16x8;   // 16 B
typedef __attribute__((ext_vector_type(4))) float f32x4;

__device__ __forceinline__ unsigned short f2bf(float x) {
  union { float f; unsigned u; } v; v.f = x;
  unsigned r = v.u + 0x7FFFu + ((v.u >> 16) & 1u);
  return (unsigned short)(r >> 16);
}
__device__ __forceinline__ float bf2f(short s) {
  union { unsigned u; float f; } t;
  t.u = ((unsigned)(unsigned short)s) << 16;
  return t.f;
}

// ---- prep: W[k][n] fp32 -> Wt[n][k] bf16 (B-frag: 8 consecutive k contiguous)
__global__ __launch_bounds__(256) void prep_wt(const float* __restrict__ W,
                                               unsigned short* __restrict__ Wt) {
  int t = blockIdx.x * 256 + threadIdx.x;
  int n = t >> 7, k = t & 127;
  Wt[n * D + k] = f2bf(W[k * D + n]);
}

// ---- prep: X fp32 row-major -> Xs bf16 SLICE-major: Xs[c][n][16 cols]
// thread t: node n = blk*32 + (t>>3), slice c = t&7; reads lane-contiguous
// float4 x4 (row fully covered by 8 lanes), owns 16 contiguous cols = slice c.
__global__ __launch_bounds__(256) void prep_x_slice(const float* __restrict__ X,
                                                    unsigned short* __restrict__ Xs) {
  int t = threadIdx.x;
  int n = blockIdx.x * 32 + (t >> 3);
  int c = t & 7;
  const float4* xr = (const float4*)(X + (long)n * D + c * SLICE_C);
  unsigned short o[16];
  #pragma unroll
  for (int k = 0; k < 4; ++k) {
    float4 v = xr[k];
    o[k * 4 + 0] = f2bf(v.x); o[k * 4 + 1] = f2bf(v.y);
    o[k * 4 + 2] = f2bf(v.z); o[k * 4 + 3] = f2bf(v.w);
  }
  unsigned short* dst = Xs + (long)c * SLICE_ELEMS + (long)n * SLICE_C;
  *(bf16x8*)(dst)     = *(bf16x8*)(o);
  *(bf16x8*)(dst + 8) = *(bf16x8*)(o + 8);
}

// ---- kernel A: sliced gather-aggregate. 1-wave blocks, 32 nodes/block.
// grid = 3125 node-blocks x 8 slices; b&7 = slice -> lands on XCD b%8.
// lane l: node n_sub = l>>1, half h = l&1 (8 cols = 16B per lane).
__global__ __launch_bounds__(64) void gin_gather_slice(
    const unsigned short* __restrict__ Xs, const int* __restrict__ colidx,
    unsigned short* __restrict__ Xp) {
  __shared__ __align__(16) int sIdx[32 * 20];   // stride 20 ints = 80B (16B-aligned)

  const int b  = blockIdx.x;
  const int c  = b & 7;
  const int nb = b >> 3;
  const int base = nb * 32;
  const int t = threadIdx.x;

  // stage 512 indices: thread t loads edges [t*8, t*8+8) = node t>>1, j0=(t&1)*8
  {
    const int4* src = (const int4*)(colidx + (long)base * DEG);
    int4 q0 = src[t * 2], q1 = src[t * 2 + 1];
    int4* dst = (int4*)(sIdx + (t >> 1) * 20 + (t & 1) * 8);
    dst[0] = q0; dst[1] = q1;
  }
  __syncthreads();

  const int n_sub = t >> 1;
  const int h = t & 1;
  const unsigned short* __restrict__ Xsc = Xs + (long)c * SLICE_ELEMS;

  int4 r0 = ((const int4*)(sIdx + n_sub * 20))[0];
  int4 r1 = ((const int4*)(sIdx + n_sub * 20))[1];
  int4 r2 = ((const int4*)(sIdx + n_sub * 20))[2];
  int4 r3 = ((const int4*)(sIdx + n_sub * 20))[3];
  int idx[16] = {r0.x, r0.y, r0.z, r0.w, r1.x, r1.y, r1.z, r1.w,
                 r2.x, r2.y, r2.z, r2.w, r3.x, r3.y, r3.z, r3.w};

  float acc[8] = {0.f, 0.f, 0.f, 0.f, 0.f, 0.f, 0.f, 0.f};
  #pragma unroll
  for (int j = 0; j < DEG; ++j) {   // 16 independent 16B L2-hit gathers
    bf16x8 v = *(const bf16x8*)(Xsc + (long)idx[j] * SLICE_C + h * 8);
    #pragma unroll
    for (int e = 0; e < 8; ++e) acc[e] += bf2f(v[e]);
  }
  bf16x8 o;
  #pragma unroll
  for (int e = 0; e < 8; ++e) o[e] = (short)f2bf(acc[e]);
  // X' row-major: node base+n_sub, cols [c*16 + h*8, +8)
  *(bf16x8*)(Xp + (long)(base + n_sub) * D + c * SLICE_C + h * 8) = o;
}

// ---- kernel B: dense MFMA GEMM  out = X'(bf16) @ Wt^T, 32 rows/block ----
__global__ __launch_bounds__(256) void gin_mm(
    const unsigned short* __restrict__ Xp, const unsigned short* __restrict__ Wt,
    float* __restrict__ out) {
  const int tid  = threadIdx.x;
  const int wave = tid >> 6;
  const int lane = tid & 63;
  const long base_node = (long)blockIdx.x * 32;
  const int fr   = lane & 15;
  const int quad = lane >> 4;

  f32x4 acc[2][2] = {{{0.f,0.f,0.f,0.f},{0.f,0.f,0.f,0.f}},
                     {{0.f,0.f,0.f,0.f},{0.f,0.f,0.f,0.f}}};
  #pragma unroll
  for (int ks = 0; ks < 4; ++ks) {
    int k0 = ks * 32 + quad * 8;
    bf16x8 a0 = *(const bf16x8*)(Xp + (base_node + fr)      * D + k0);
    bf16x8 a1 = *(const bf16x8*)(Xp + (base_node + 16 + fr) * D + k0);
    #pragma unroll
    for (int nt = 0; nt < 2; ++nt) {
      int n = (wave * 2 + nt) * 16 + fr;
      bf16x8 bfrag = *(const bf16x8*)(&Wt[n * D + k0]);
      acc[0][nt] = __builtin_amdgcn_mfma_f32_16x16x32_bf16(a0, bfrag, acc[0][nt], 0, 0, 0);
      acc[1][nt] = __builtin_amdgcn_mfma_f32_16x16x32_bf16(a1, bfrag, acc[1][nt], 0, 0, 0);
    }
  }
  #pragma unroll
  for (int mt = 0; mt < 2; ++mt)
    #pragma unroll
    for (int nt = 0; nt < 2; ++nt) {
      int col = (wave * 2 + nt) * 16 + fr;
      long rowbase = base_node + mt * 16 + quad * 4;
      #pragma unroll
      for (int r = 0; r < 4; ++r)
        out[(rowbase + r) * D + col] = acc[mt][nt][r];
    }
}

// ======================= R4 fallback path (ws too small) =====================
__global__ __launch_bounds__(256) void prep_x(const float* __restrict__ X,
                                              unsigned short* __restrict__ Xb) {
  long t = (long)blockIdx.x * 256 + threadIdx.x;
  float4 v = ((const float4*)X)[t];
  ushort4 o;
  o.x = f2bf(v.x); o.y = f2bf(v.y); o.z = f2bf(v.z); o.w = f2bf(v.w);
  ((ushort4*)Xb)[t] = o;
}

#define MT 32
#define XPS 136
__global__ __launch_bounds__(256, 4) void gin_fused_bf16(
    const unsigned short* __restrict__ Xb, const int* __restrict__ colidx,
    const unsigned short* __restrict__ Wt, float* __restrict__ out) {
  __shared__ __align__(16) unsigned short sXp[MT * XPS];
  __shared__ __align__(16) int sIdx[MT * DEG];
  const int tid  = threadIdx.x;
  const int wave = tid >> 6;
  const int lane = tid & 63;
  const long base_node = (long)blockIdx.x * MT;
  ((int2*)sIdx)[tid] = ((const int2*)(colidx + base_node * DEG))[tid];
  __syncthreads();
  const int q = lane >> 4, l = lane & 15;
  #pragma unroll
  for (int p = 0; p < 2; ++p) {
    int local = wave * 8 + p * 4 + q;
    float acc[8] = {0.f, 0.f, 0.f, 0.f, 0.f, 0.f, 0.f, 0.f};
    #pragma unroll
    for (int j = 0; j < DEG; ++j) {
      int cidx = sIdx[local * DEG + j];
      bf16x8 v = *(const bf16x8*)(Xb + (long)cidx * D + l * 8);
      #pragma unroll
      for (int e = 0; e < 8; ++e) acc[e] += bf2f(v[e]);
    }
    bf16x8 o;
    #pragma unroll
    for (int e = 0; e < 8; ++e) o[e] = (short)f2bf(acc[e]);
    *(bf16x8*)(&sXp[local * XPS + l * 8]) = o;
  }
  __syncthreads();
  const int fr = lane & 15, quad = lane >> 4;
  f32x4 acc[2][2] = {{{0.f,0.f,0.f,0.f},{0.f,0.f,0.f,0.f}},
                     {{0.f,0.f,0.f,0.f},{0.f,0.f,0.f,0.f}}};
  #pragma unroll
  for (int ks = 0; ks < 4; ++ks) {
    int k0 = ks * 32 + quad * 8;
    bf16x8 a0 = *(const bf16x8*)(&sXp[fr        * XPS + k0]);
    bf16x8 a1 = *(const bf16x8*)(&sXp[(16 + fr) * XPS + k0]);
    #pragma unroll
    for (int nt = 0; nt < 2; ++nt) {
      int n = (wave * 2 + nt) * 16 + fr;
      bf16x8 bfrag = *(const bf16x8*)(&Wt[n * D + k0]);
      acc[0][nt] = __builtin_amdgcn_mfma_f32_16x16x32_bf16(a0, bfrag, acc[0][nt], 0, 0, 0);
      acc[1][nt] = __builtin_amdgcn_mfma_f32_16x16x32_bf16(a1, bfrag, acc[1][nt], 0, 0, 0);
    }
  }
  #pragma unroll
  for (int mt = 0; mt < 2; ++mt)
    #pragma unroll
    for (int nt = 0; nt < 2; ++nt) {
      int col = (wave * 2 + nt) * 16 + fr;
      long rowbase = base_node + mt * 16 + quad * 4;
      #pragma unroll
      for (int r = 0; r < 4; ++r)
        out[(rowbase + r) * D + col] = acc[mt][nt][r];
    }
}

extern "C" void kernel_launch(void* const* d_in, const int* in_sizes, int n_in,
                              void* d_out, int out_size, void* d_ws, size_t ws_size,
                              hipStream_t stream) {
  const float* X      = (const float*)d_in[0];
  const float* W      = (const float*)d_in[1];
  const int*   colidx = (const int*)d_in[3];
  float* out = (float*)d_out;

  if (ws_size >= (size_t)WS_NEW) {
    unsigned short* Xs = (unsigned short*)d_ws;                         // 25.6MB
    unsigned short* Xp = (unsigned short*)((char*)d_ws + XS_BYTES);     // 25.6MB
    unsigned short* Wt = (unsigned short*)((char*)d_ws + XS_BYTES + XP_BYTES);
    hipLaunchKernelGGL(prep_wt, dim3(64), dim3(256), 0, stream, W, Wt);
    hipLaunchKernelGGL(prep_x_slice, dim3(3125), dim3(256), 0, stream, X, Xs);
    hipLaunchKernelGGL(gin_gather_slice, dim3(3125 * NSLICE), dim3(64), 0, stream,
                       Xs, colidx, Xp);
    hipLaunchKernelGGL(gin_mm, dim3(3125), dim3(256), 0, stream, Xp, Wt, out);
  } else {
    unsigned short* Xb = (unsigned short*)d_ws;                         // 25.6MB
    unsigned short* Wt = (unsigned short*)((char*)d_ws + XS_BYTES);
    hipLaunchKernelGGL(prep_wt, dim3(64), dim3(256), 0, stream, W, Wt);
    hipLaunchKernelGGL(prep_x, dim3(12500), dim3(256), 0, stream, X, Xb);
    hipLaunchKernelGGL(gin_fused_bf16, dim3(NNODES / MT), dim3(256), 0, stream,
                       Xb, colidx, Wt, out);
  }
}

// Round 6
// 227.227 us; speedup vs baseline: 1.0967x; 1.0967x over previous
//
#include <hip/hip_runtime.h>

// GINConv fused: out[r] = (sum_{j<16} X[col[16r+j]]) @ W
// N=100000, DEG=16, D=128.
// R6: gather concurrency wall (R3/R4: compiler caps ~5 in-flight loads/wave
// via VGPR rationing). Fix: global_load_lds async gathers — no dest VGPRs,
// 16 outstanding 1KB gather-insts per wave, drain once, accumulate from LDS.
// R5 lesson: FETCH is not binding (58MB vs 175MB at equal dur) — slicing dropped.

#define NNODES 100000
#define DEG 16
#define D 128
#define MT 16                       // nodes per block
#define XPS 136                     // sXp row stride (272B: 2-way alias, free)

#define XB_BYTES (100000L * 128 * 2)   // 25,600,000 bf16 X
#define WT_BYTES (128L * 128 * 2)      // 32,768
#define WS_NEEDED (XB_BYTES + WT_BYTES)

typedef __attribute__((ext_vector_type(8))) short bf16x8;   // 16 B
typedef __attribute__((ext_vector_type(4))) float f32x4;

__device__ __forceinline__ unsigned short f2bf(float x) {
  union { float f; unsigned u; } v; v.f = x;
  unsigned r = v.u + 0x7FFFu + ((v.u >> 16) & 1u);
  return (unsigned short)(r >> 16);
}
__device__ __forceinline__ float bf2f(short s) {
  union { unsigned u; float f; } t;
  t.u = ((unsigned)(unsigned short)s) << 16;
  return t.f;
}

// ---- prep: W[k][n] fp32 -> Wt[n][k] bf16 (B-frag: 8 consecutive k contiguous)
__global__ __launch_bounds__(256) void prep_wt(const float* __restrict__ W,
                                               unsigned short* __restrict__ Wt) {
  int t = blockIdx.x * 256 + threadIdx.x;
  int n = t >> 7, k = t & 127;
  Wt[n * D + k] = f2bf(W[k * D + n]);
}

// ---- prep: X fp32 -> bf16 row-major, coalesced
__global__ __launch_bounds__(256) void prep_x(const float* __restrict__ X,
                                              unsigned short* __restrict__ Xb) {
  long t = (long)blockIdx.x * 256 + threadIdx.x;
  float4 v = ((const float4*)X)[t];
  ushort4 o;
  o.x = f2bf(v.x); o.y = f2bf(v.y); o.z = f2bf(v.z); o.w = f2bf(v.w);
  ((ushort4*)Xb)[t] = o;
}

// ---- main: async-DMA gather + LDS accumulate + MFMA, fused ----
// 256 thr = 4 waves; 16 nodes/block; wave w owns nodes 4w..4w+3 = 64 rows.
// Issue: 16 global_load_lds_dwordx4 per wave (4 rows x 16 lanes each),
// all in flight at once (no dest VGPRs). LDS: 4 x 16 KB row regions.
__global__ __launch_bounds__(256) void gin_async(
    const unsigned short* __restrict__ Xb, const int* __restrict__ colidx,
    const unsigned short* __restrict__ Wt, float* __restrict__ out) {
  __shared__ __align__(16) unsigned short sRows[4 * 64 * D];  // 64 KB
  __shared__ __align__(16) int sIdx[MT * DEG];                // 1 KB
  __shared__ __align__(16) unsigned short sXp[MT * XPS];      // 4.25 KB

  const int tid  = threadIdx.x;
  const int wave = tid >> 6;
  const int lane = tid & 63;
  const long base_node = (long)blockIdx.x * MT;

  // stage 256 indices (1 int per thread, coalesced)
  sIdx[tid] = colidx[base_node * DEG + tid];
  __syncthreads();

  // ---- issue phase: 16 async gathers per wave, back-to-back ----
  // inst i covers block-rows w*64 + i*4 + (lane>>4); lane&15 = 16B chunk.
  {
    const int rsel  = lane >> 4;    // row within instruction (0..3)
    const int chunk = lane & 15;    // 16B chunk within 256B row
    #pragma unroll
    for (int i = 0; i < 16; ++i) {
      int c = sIdx[wave * 64 + i * 4 + rsel];          // LDS broadcast read
      const unsigned short* src = Xb + (long)c * D + chunk * 8;
      unsigned short* dst = &sRows[wave * (64 * D) + i * 4 * D];  // wave-uniform
      __builtin_amdgcn_global_load_lds(
          (const __attribute__((address_space(1))) void*)src,
          (__attribute__((address_space(3))) void*)dst, 16, 0, 0);
    }
  }
  __syncthreads();   // drains vmcnt(0) before barrier (compiler semantics)

  // ---- accumulate phase: quarter-wave q owns node w*4+q ----
  {
    const int q = lane >> 4;
    const int l = lane & 15;
    const unsigned short* wreg = &sRows[wave * (64 * D)];
    float acc[8] = {0.f, 0.f, 0.f, 0.f, 0.f, 0.f, 0.f, 0.f};
    #pragma unroll
    for (int j = 0; j < DEG; ++j) {
      bf16x8 v = *(const bf16x8*)(wreg + (q * DEG + j) * D + l * 8);  // ds_read_b128
      #pragma unroll
      for (int e = 0; e < 8; ++e) acc[e] += bf2f(v[e]);
    }
    bf16x8 o;
    #pragma unroll
    for (int e = 0; e < 8; ++e) o[e] = (short)f2bf(acc[e]);
    *(bf16x8*)(&sXp[(wave * 4 + q) * XPS + l * 8]) = o;
  }
  __syncthreads();

  // ---- MFMA 16x16x32: single m-tile (16 nodes); wave w -> cols [32w,32w+32) ----
  const int fr   = lane & 15;
  const int quad = lane >> 4;
  f32x4 acc2[2] = {{0.f,0.f,0.f,0.f},{0.f,0.f,0.f,0.f}};
  #pragma unroll
  for (int ks = 0; ks < 4; ++ks) {
    int k0 = ks * 32 + quad * 8;
    bf16x8 a = *(const bf16x8*)(&sXp[fr * XPS + k0]);
    #pragma unroll
    for (int nt = 0; nt < 2; ++nt) {
      int n = wave * 32 + nt * 16 + fr;
      bf16x8 bfrag = *(const bf16x8*)(&Wt[n * D + k0]);
      acc2[nt] = __builtin_amdgcn_mfma_f32_16x16x32_bf16(a, bfrag, acc2[nt], 0, 0, 0);
    }
  }
  #pragma unroll
  for (int nt = 0; nt < 2; ++nt) {
    int col = wave * 32 + nt * 16 + fr;
    long rowbase = base_node + quad * 4;
    #pragma unroll
    for (int r = 0; r < 4; ++r)
      out[(rowbase + r) * D + col] = acc2[nt][r];
  }
}

// ======================= R4 fallback path (ws too small) =====================
#define FMT 32
__global__ __launch_bounds__(256, 4) void gin_fused_bf16(
    const unsigned short* __restrict__ Xb, const int* __restrict__ colidx,
    const unsigned short* __restrict__ Wt, float* __restrict__ out) {
  __shared__ __align__(16) unsigned short sXp[FMT * XPS];
  __shared__ __align__(16) int sIdx[FMT * DEG];
  const int tid  = threadIdx.x;
  const int wave = tid >> 6;
  const int lane = tid & 63;
  const long base_node = (long)blockIdx.x * FMT;
  ((int2*)sIdx)[tid] = ((const int2*)(colidx + base_node * DEG))[tid];
  __syncthreads();
  const int q = lane >> 4, l = lane & 15;
  #pragma unroll
  for (int p = 0; p < 2; ++p) {
    int local = wave * 8 + p * 4 + q;
    float acc[8] = {0.f, 0.f, 0.f, 0.f, 0.f, 0.f, 0.f, 0.f};
    #pragma unroll
    for (int j = 0; j < DEG; ++j) {
      int cidx = sIdx[local * DEG + j];
      bf16x8 v = *(const bf16x8*)(Xb + (long)cidx * D + l * 8);
      #pragma unroll
      for (int e = 0; e < 8; ++e) acc[e] += bf2f(v[e]);
    }
    bf16x8 o;
    #pragma unroll
    for (int e = 0; e < 8; ++e) o[e] = (short)f2bf(acc[e]);
    *(bf16x8*)(&sXp[local * XPS + l * 8]) = o;
  }
  __syncthreads();
  const int fr = lane & 15, quad = lane >> 4;
  f32x4 acc[2][2] = {{{0.f,0.f,0.f,0.f},{0.f,0.f,0.f,0.f}},
                     {{0.f,0.f,0.f,0.f},{0.f,0.f,0.f,0.f}}};
  #pragma unroll
  for (int ks = 0; ks < 4; ++ks) {
    int k0 = ks * 32 + quad * 8;
    bf16x8 a0 = *(const bf16x8*)(&sXp[fr        * XPS + k0]);
    bf16x8 a1 = *(const bf16x8*)(&sXp[(16 + fr) * XPS + k0]);
    #pragma unroll
    for (int nt = 0; nt < 2; ++nt) {
      int n = (wave * 2 + nt) * 16 + fr;
      bf16x8 bfrag = *(const bf16x8*)(&Wt[n * D + k0]);
      acc[0][nt] = __builtin_amdgcn_mfma_f32_16x16x32_bf16(a0, bfrag, acc[0][nt], 0, 0, 0);
      acc[1][nt] = __builtin_amdgcn_mfma_f32_16x16x32_bf16(a1, bfrag, acc[1][nt], 0, 0, 0);
    }
  }
  #pragma unroll
  for (int mt = 0; mt < 2; ++mt)
    #pragma unroll
    for (int nt = 0; nt < 2; ++nt) {
      int col = (wave * 2 + nt) * 16 + fr;
      long rowbase = base_node + mt * 16 + quad * 4;
      #pragma unroll
      for (int r = 0; r < 4; ++r)
        out[(rowbase + r) * D + col] = acc[mt][nt][r];
    }
}

extern "C" void kernel_launch(void* const* d_in, const int* in_sizes, int n_in,
                              void* d_out, int out_size, void* d_ws, size_t ws_size,
                              hipStream_t stream) {
  const float* X      = (const float*)d_in[0];
  const float* W      = (const float*)d_in[1];
  const int*   colidx = (const int*)d_in[3];
  float* out = (float*)d_out;

  unsigned short* Xb = (unsigned short*)d_ws;                       // 25.6 MB
  unsigned short* Wt = (unsigned short*)((char*)d_ws + XB_BYTES);   // 32 KB
  hipLaunchKernelGGL(prep_wt, dim3(64), dim3(256), 0, stream, W, Wt);
  hipLaunchKernelGGL(prep_x, dim3(12500), dim3(256), 0, stream, X, Xb);
  if (ws_size >= (size_t)WS_NEEDED) {
    hipLaunchKernelGGL(gin_async, dim3(NNODES / MT), dim3(256), 0, stream,
                       Xb, colidx, Wt, out);
  } else {
    hipLaunchKernelGGL(gin_fused_bf16, dim3(NNODES / FMT), dim3(256), 0, stream,
                       Xb, colidx, Wt, out);
  }
}